// Round 7
// baseline (392.339 us; speedup 1.0000x reference)
//
#include <hip/hip_runtime.h>
#include <hip/hip_bf16.h>

typedef _Float16 half8  __attribute__((ext_vector_type(8)));
typedef _Float16 half4v __attribute__((ext_vector_type(4)));
typedef float    f32x4  __attribute__((ext_vector_type(4)));

#define N_NODES 100000
#define N_EDGES 3200000
#define SH_STRIDE 100096   // fallback shadow stride (floats)
#define NBUCK 391          // 256 nodes per bucket (4 sage tiles)
#define CAP   9216         // pairs/bucket: mean 8192 + 11 sigma
#define CHUNK 8192         // edges per bin block
#define NBIN  391          // ceil(N_EDGES/CHUNK)
#define NPK   64           // pack blocks appended to bin grid

// ---------------------------------------------------------------------------
// Merged bin + pack kernel.
// blocks [0,NBIN): bin edges by dst>>8 into per-bucket 4B packed records:
//   packed = (fp32_bits & 0xFFFFFF00) | (dst & 255)   (rel err <= 2^-16)
//   LDS histogram -> one global reservation atomic per nonzero bucket
//   (NBIN*NBUCK ~ 153K total, ~15/cyc measured R5->R6) -> semi-coalesced runs.
// blocks [NBIN, NBIN+NPK): pack weights fp32->fp16 and build park[] table:
//   park[l*512 + j]       = we_l[j]   (concat-edge column; 0 for layer 6)
//   park[l*512 + 256 + j] = bias_l[j]
//   park[3584 + j]        = wr3[j];  park[3840] = br3[0]
// ---------------------------------------------------------------------------
__global__ __launch_bounds__(256) void binpack(
    const float* __restrict__ ef, const int* __restrict__ dst,
    const float* __restrict__ W1,  const float* __restrict__ Wm1,
    const float* __restrict__ Wm2, const float* __restrict__ Wm3,
    const float* __restrict__ Wm4, const float* __restrict__ Wr1,
    const float* __restrict__ Wr2,
    const float* __restrict__ b1,  const float* __restrict__ bm1,
    const float* __restrict__ bm2, const float* __restrict__ bm3,
    const float* __restrict__ bm4, const float* __restrict__ br1,
    const float* __restrict__ br2, const float* __restrict__ wr3,
    const float* __restrict__ br3,
    int* __restrict__ cursor, unsigned* __restrict__ pairs,
    _Float16* __restrict__ Wp, float* __restrict__ park, int do_bin) {

    if (do_bin && blockIdx.x < NBIN) {
        __shared__ int hist[NBUCK];
        __shared__ int base[NBUCK];
        const int start = blockIdx.x * CHUNK;
        const int end   = min(start + CHUNK, N_EDGES);
        for (int b = threadIdx.x; b < NBUCK; b += 256) hist[b] = 0;
        __syncthreads();
        for (int i = start + threadIdx.x * 4; i < end; i += 1024) {
            const int4 d = *(const int4*)&dst[i];
            atomicAdd(&hist[d.x >> 8], 1);
            atomicAdd(&hist[d.y >> 8], 1);
            atomicAdd(&hist[d.z >> 8], 1);
            atomicAdd(&hist[d.w >> 8], 1);
        }
        __syncthreads();
        for (int b = threadIdx.x; b < NBUCK; b += 256) {
            const int c = hist[b];
            base[b] = b * CAP + ((c > 0) ? atomicAdd(&cursor[b], c) : 0);
            hist[b] = 0;
        }
        __syncthreads();
        for (int i = start + threadIdx.x * 4; i < end; i += 1024) {
            const int4   d = *(const int4*)&dst[i];
            const float4 f = *(const float4*)&ef[i];
            {   const int b = d.x >> 8;
                const int s = base[b] + atomicAdd(&hist[b], 1);
                if (s < b * CAP + CAP)
                    pairs[s] = (__float_as_uint(f.x) & 0xFFFFFF00u) | (unsigned)(d.x & 255); }
            {   const int b = d.y >> 8;
                const int s = base[b] + atomicAdd(&hist[b], 1);
                if (s < b * CAP + CAP)
                    pairs[s] = (__float_as_uint(f.y) & 0xFFFFFF00u) | (unsigned)(d.y & 255); }
            {   const int b = d.z >> 8;
                const int s = base[b] + atomicAdd(&hist[b], 1);
                if (s < b * CAP + CAP)
                    pairs[s] = (__float_as_uint(f.z) & 0xFFFFFF00u) | (unsigned)(d.z & 255); }
            {   const int b = d.w >> 8;
                const int s = base[b] + atomicAdd(&hist[b], 1);
                if (s < b * CAP + CAP)
                    pairs[s] = (__float_as_uint(f.w) & 0xFFFFFF00u) | (unsigned)(d.w & 255); }
        }
    } else {
        const float* srcs[7] = {W1, Wm1, Wm2, Wm3, Wm4, Wr1, Wr2};
        const float* bias[7] = {b1, bm1, bm2, bm3, bm4, br1, br2};
        const int pb  = do_bin ? ((int)blockIdx.x - NBIN) : (int)blockIdx.x;
        const int gid = pb * 256 + threadIdx.x;
        const int gsz = NPK * 256;
        for (int i = gid; i < 425984; i += gsz) {
            int job, row, k, stride;
            if (i < 32768) { job = 0; row = i >> 7; k = i & 127; stride = 129; }
            else {
                int t = i - 32768; job = 1 + (t >> 16); int w = t & 65535;
                row = w >> 8; k = w & 255; stride = (job == 6) ? 256 : 257;
            }
            Wp[i] = (_Float16)srcs[job][row * stride + k];
        }
        for (int i = gid; i < 1536; i += gsz) {
            const int job = i >> 8, row = i & 255;
            const int stride = (job == 0) ? 129 : 257;
            const int kin    = (job == 0) ? 128 : 256;
            park[job * 512 + row] = srcs[job][row * stride + kin];
        }
        for (int i = gid; i < 256; i += gsz) park[6 * 512 + i] = 0.f;
        for (int i = gid; i < 1792; i += gsz)
            park[(i >> 8) * 512 + 256 + (i & 255)] = bias[i >> 8][i & 255];
        for (int i = gid; i < 256; i += gsz) park[3584 + i] = wr3[i];
        if (gid == 0) park[3840] = br3[0];
    }
}

// fallback: device-scope split-4 scatter (known-good)
__global__ void scatter4(const float4* __restrict__ ef4,
                         const int4* __restrict__ dst4,
                         float* __restrict__ e) {
    const int n4 = N_EDGES / 4;
    for (int i = blockIdx.x * blockDim.x + threadIdx.x; i < n4;
         i += gridDim.x * blockDim.x) {
        const float4 f = ef4[i];
        const int4   d = dst4[i];
        atomicAdd(&e[d.x], f.x);
        atomicAdd(&e[SH_STRIDE + d.y], f.y);
        atomicAdd(&e[2 * SH_STRIDE + d.z], f.z);
        atomicAdd(&e[3 * SH_STRIDE + d.w], f.w);
    }
}

// ---------------------------------------------------------------------------
// One layer, ping-pong: reads Hin, writes Hout (disjoint) -> SINGLE barrier.
// Wave owns 64 cols x 64 nodes (jt4 x mt4). a-frag = W rows from global/L2,
// prefetched one k-step ahead; b-frag = H rows via ds_read_b128. Epilogue
// constants (we, bias) preloaded to registers from park (no LDS staging ->
// no second barrier). D: col=lane&15 -> node, row=quad*4+r -> 4 consecutive
// output features -> packed 8B LDS stores.
// ---------------------------------------------------------------------------
template<int K>
__device__ __forceinline__ void layer_mm(const _Float16* __restrict__ Wl,
                                         const _Float16 (* __restrict__ Hin)[264],
                                         _Float16 (* __restrict__ Hout)[264],
                                         const float* __restrict__ es,
                                         const float* __restrict__ parkl,
                                         int wave, int m_, int quad) {
    f32x4 acc[4][4];
    #pragma unroll
    for (int jt = 0; jt < 4; ++jt)
        #pragma unroll
        for (int mt = 0; mt < 4; ++mt)
            acc[jt][mt] = (f32x4){0.f, 0.f, 0.f, 0.f};

    const int jb0 = wave * 64 + quad * 4;
    float4 w4[4], bb[4];
    #pragma unroll
    for (int jt = 0; jt < 4; ++jt) {
        w4[jt] = *(const float4*)&parkl[jt * 16 + jb0];
        bb[jt] = *(const float4*)&parkl[256 + jt * 16 + jb0];
    }

    const _Float16* __restrict__ wp = Wl + (size_t)(wave * 64 + m_) * K + quad * 8;

    half8 a[4];
    #pragma unroll
    for (int jt = 0; jt < 4; ++jt)
        a[jt] = *(const half8*)(wp + jt * 16 * K);

    #pragma unroll
    for (int kk = 0; kk < K; kk += 32) {
        half8 a2[4];
        if (kk + 32 < K) {
            #pragma unroll
            for (int jt = 0; jt < 4; ++jt)
                a2[jt] = *(const half8*)(wp + jt * 16 * K + kk + 32);
        }
        half8 b[4];
        #pragma unroll
        for (int mt = 0; mt < 4; ++mt)
            b[mt] = *(const half8*)&Hin[mt * 16 + m_][kk + quad * 8];
        #pragma unroll
        for (int jt = 0; jt < 4; ++jt)
            #pragma unroll
            for (int mt = 0; mt < 4; ++mt)
                acc[jt][mt] = __builtin_amdgcn_mfma_f32_16x16x32_f16(
                    a[jt], b[mt], acc[jt][mt], 0, 0, 0);
        if (kk + 32 < K) {
            #pragma unroll
            for (int jt = 0; jt < 4; ++jt) a[jt] = a2[jt];
        }
    }

    // epilogue straight into the other buffer — no pre-barrier needed
    #pragma unroll
    for (int jt = 0; jt < 4; ++jt) {
        const int jbase = jb0 + jt * 16;
        #pragma unroll
        for (int mt = 0; mt < 4; ++mt) {
            const int node = mt * 16 + m_;
            const float ev = es[node];
            half4v h;
            h[0] = (_Float16)fmaxf(acc[jt][mt][0] + ev * w4[jt].x + bb[jt].x, 0.f);
            h[1] = (_Float16)fmaxf(acc[jt][mt][1] + ev * w4[jt].y + bb[jt].y, 0.f);
            h[2] = (_Float16)fmaxf(acc[jt][mt][2] + ev * w4[jt].z + bb[jt].z, 0.f);
            h[3] = (_Float16)fmaxf(acc[jt][mt][3] + ev * w4[jt].w + bb[jt].w, 0.f);
            *(half4v*)&Hout[node][jbase] = h;
        }
    }
    __syncthreads();   // single drain per layer
}

// ---------------------------------------------------------------------------
__global__ __launch_bounds__(256) void sage_fused(
    const float* __restrict__ node_feat,
    const int* __restrict__ cursor, const unsigned* __restrict__ pairs,
    const float* __restrict__ esh, int nsh,
    const _Float16* __restrict__ Wpack, const float* __restrict__ park,
    float* __restrict__ out) {

    __shared__ _Float16 Hs[2][64][264];   // ping-pong, +8-half pad
    __shared__ float es[64];
    __shared__ float wf[256];
    __shared__ float red[4][64];

    const int tid  = threadIdx.x;
    const int wave = tid >> 6;
    const int lane = tid & 63;
    const int m_   = lane & 15;
    const int quad = lane >> 4;
    const int node0 = blockIdx.x * 64;

    if (tid < 64) es[tid] = 0.f;
    __syncthreads();

    // ---- stage node_feat tile (fp32 -> fp16) into Hs[0] ----
    for (int idx = tid; idx < 64 * 16; idx += 256) {
        const int row = idx >> 4, g = idx & 15;
        int node = node0 + row; if (node >= N_NODES) node = N_NODES - 1;
        const float4* src = (const float4*)(node_feat + (size_t)node * 128 + g * 8);
        const float4 v0 = src[0], v1 = src[1];
        half8 h;
        h[0] = (_Float16)v0.x; h[1] = (_Float16)v0.y;
        h[2] = (_Float16)v0.z; h[3] = (_Float16)v0.w;
        h[4] = (_Float16)v1.x; h[5] = (_Float16)v1.y;
        h[6] = (_Float16)v1.z; h[7] = (_Float16)v1.w;
        *(half8*)&Hs[0][row][g * 8] = h;
    }
    // ---- edge aggregate for this 64-node tile ----
    if (nsh == 0) {
        const int bucket = blockIdx.x >> 2;
        const int want   = blockIdx.x & 3;
        const int cnt = min(cursor[bucket], CAP);
        const unsigned* __restrict__ pp = pairs + (size_t)bucket * CAP;
        for (int i = tid; i < cnt; i += 256) {
            const unsigned p = pp[i];
            if ((int)((p >> 6) & 3u) == want)
                atomicAdd(&es[p & 63u], __uint_as_float(p & 0xFFFFFF00u));
        }
    } else if (tid < 64) {
        int node = node0 + tid; if (node >= N_NODES) node = N_NODES - 1;
        float s = 0.f;
        for (int sh = 0; sh < nsh; ++sh) s += esh[(size_t)sh * SH_STRIDE + node];
        es[tid] = s;
    }
    __syncthreads();

    // layer 0: K=128, Hs[0] -> Hs[1]; layers 1..6: K=256, alternating
    layer_mm<128>(Wpack, Hs[0], Hs[1], es, park, wave, m_, quad);
    for (int l = 1; l < 7; ++l)
        layer_mm<256>(Wpack + 32768 + (l - 1) * 65536,
                      Hs[l & 1], Hs[(l & 1) ^ 1], es, park + l * 512,
                      wave, m_, quad);
    // final activations in Hs[1]

    // ---- final 256 -> 1 dot (fp32) ----
    wf[tid] = park[3584 + tid];
    __syncthreads();
    {
        const int row = tid & 63, seg = tid >> 6;
        const _Float16* hp = &Hs[1][row][seg * 64];
        const float* wpt = &wf[seg * 64];
        float s = 0.f;
        #pragma unroll 8
        for (int k = 0; k < 64; ++k) s += (float)hp[k] * wpt[k];
        red[seg][row] = s;
    }
    __syncthreads();
    if (tid < 64) {
        const int node = node0 + tid;
        if (node < N_NODES)
            out[node] = red[0][tid] + red[1][tid] + red[2][tid] + red[3][tid]
                        + park[3840];
    }
}

// ---------------------------------------------------------------------------
extern "C" void kernel_launch(void* const* d_in, const int* in_sizes, int n_in,
                              void* d_out, int out_size, void* d_ws,
                              size_t ws_size, hipStream_t stream) {
    const float* node_feat = (const float*)d_in[0];
    const float* edge_feat = (const float*)d_in[1];
    const int*   edge_dst  = (const int*)d_in[2];
    const float* W1  = (const float*)d_in[3];  const float* b1  = (const float*)d_in[4];
    const float* Wm1 = (const float*)d_in[5];  const float* bm1 = (const float*)d_in[6];
    const float* Wm2 = (const float*)d_in[7];  const float* bm2 = (const float*)d_in[8];
    const float* Wm3 = (const float*)d_in[9];  const float* bm3 = (const float*)d_in[10];
    const float* Wm4 = (const float*)d_in[11]; const float* bm4 = (const float*)d_in[12];
    const float* Wr1 = (const float*)d_in[13]; const float* br1 = (const float*)d_in[14];
    const float* Wr2 = (const float*)d_in[15]; const float* br2 = (const float*)d_in[16];
    const float* Wr3 = (const float*)d_in[17]; const float* br3 = (const float*)d_in[18];
    float* out = (float*)d_out;

    // ws layout: cursor | Wp | park | pairs (or fallback shadows)
    char* ws = (char*)d_ws;
    int*      cursor = (int*)ws;                           // 2048 B reserved
    _Float16* Wp     = (_Float16*)(ws + 2048);             // 851968 B
    float*    park   = (float*)(ws + 854016);              // 16384 B
    unsigned* pairs  = (unsigned*)(ws + 870400);           // NBUCK*CAP*4 B
    float*    esh    = (float*)(ws + 870400);              // fallback shadows

    const size_t need_bins = 870400 + (size_t)NBUCK * CAP * 4;   // ~15.3 MB
    const bool use_bins = (ws_size >= need_bins);

    const int nblk = (N_NODES + 63) / 64;   // 1563

    if (use_bins) {
        hipMemsetAsync(cursor, 0, NBUCK * sizeof(int), stream);
        binpack<<<NBIN + NPK, 256, 0, stream>>>(
            edge_feat, edge_dst, W1, Wm1, Wm2, Wm3, Wm4, Wr1, Wr2,
            b1, bm1, bm2, bm3, bm4, br1, br2, Wr3, br3,
            cursor, pairs, Wp, park, 1);
        sage_fused<<<nblk, 256, 0, stream>>>(node_feat, cursor, pairs,
                                             nullptr, 0, Wp, park, out);
    } else {
        binpack<<<NPK, 256, 0, stream>>>(
            edge_feat, edge_dst, W1, Wm1, Wm2, Wm3, Wm4, Wr1, Wr2,
            b1, bm1, bm2, bm3, bm4, br1, br2, Wr3, br3,
            cursor, pairs, Wp, park, 0);
        hipMemsetAsync(esh, 0, (size_t)4 * SH_STRIDE * 4, stream);
        scatter4<<<3125, 256, 0, stream>>>((const float4*)edge_feat,
                                           (const int4*)edge_dst, esh);
        sage_fused<<<nblk, 256, 0, stream>>>(node_feat, nullptr, nullptr,
                                             esh, 4, Wp, park, out);
    }
}

// Round 8
// 294.554 us; speedup vs baseline: 1.3320x; 1.3320x over previous
//
#include <hip/hip_runtime.h>
#include <hip/hip_bf16.h>

typedef _Float16 half8  __attribute__((ext_vector_type(8)));
typedef _Float16 half4v __attribute__((ext_vector_type(4)));
typedef float    f32x4  __attribute__((ext_vector_type(4)));

#define N_NODES 100000
#define N_EDGES 3200000
#define SH_STRIDE 100096   // fallback shadow stride (floats)
#define NBUCK 782          // 128 nodes per bucket == one sage tile
#define CAP   5120         // pairs/bucket: mean 4096 + 16 sigma
#define CHUNK 16384        // edges per bin block (1024 threads, 16/thread)
#define NBIN  196          // ceil(N_EDGES/CHUNK)
#define NPK   16           // pack blocks appended to bin grid

// ---------------------------------------------------------------------------
// Merged bin + pack kernel, 1024-thread blocks.
// bin blocks [0,NBIN): 16 edges/thread held in REGISTERS across phases:
//   phase1 LDS histogram by dst>>7 -> one global reservation atomic per
//   nonzero bucket (~153K total) -> phase2 packed 4B record writes:
//     rec = (fp32_bits & 0xFFFFFF00) | (dst & 127)    (rel err <= 2^-16)
// pack blocks [NBIN,NBIN+NPK): weights fp32->fp16 + park[] table:
//   park[l*512+j]=we_l[j]; park[l*512+256+j]=bias_l[j];
//   park[3584+j]=wr3[j]; park[3840]=br3[0]
// ---------------------------------------------------------------------------
__global__ __launch_bounds__(1024) void binpack(
    const float* __restrict__ ef, const int* __restrict__ dst,
    const float* __restrict__ W1,  const float* __restrict__ Wm1,
    const float* __restrict__ Wm2, const float* __restrict__ Wm3,
    const float* __restrict__ Wm4, const float* __restrict__ Wr1,
    const float* __restrict__ Wr2,
    const float* __restrict__ b1,  const float* __restrict__ bm1,
    const float* __restrict__ bm2, const float* __restrict__ bm3,
    const float* __restrict__ bm4, const float* __restrict__ br1,
    const float* __restrict__ br2, const float* __restrict__ wr3,
    const float* __restrict__ br3,
    int* __restrict__ cursor, unsigned* __restrict__ pairs,
    _Float16* __restrict__ Wp, float* __restrict__ park, int do_bin) {

    if (do_bin && blockIdx.x < NBIN) {
        __shared__ int hist[NBUCK];
        __shared__ int base[NBUCK];
        const int start = blockIdx.x * CHUNK;
        const int end   = min(start + CHUNK, N_EDGES);
        const int tid   = threadIdx.x;
        for (int b = tid; b < NBUCK; b += 1024) hist[b] = 0;
        __syncthreads();

        int4   dreg[4];
        float4 freg[4];
        #pragma unroll
        for (int it = 0; it < 4; ++it) {
            const int i = start + it * 4096 + tid * 4;
            if (i < end) {
                dreg[it] = *(const int4*)&dst[i];
                freg[it] = *(const float4*)&ef[i];
                atomicAdd(&hist[dreg[it].x >> 7], 1);
                atomicAdd(&hist[dreg[it].y >> 7], 1);
                atomicAdd(&hist[dreg[it].z >> 7], 1);
                atomicAdd(&hist[dreg[it].w >> 7], 1);
            }
        }
        __syncthreads();
        for (int b = tid; b < NBUCK; b += 1024) {
            const int c = hist[b];
            base[b] = b * CAP + ((c > 0) ? atomicAdd(&cursor[b], c) : 0);
            hist[b] = 0;
        }
        __syncthreads();
        #pragma unroll
        for (int it = 0; it < 4; ++it) {
            const int i = start + it * 4096 + tid * 4;
            if (i < end) {
                const int4   d = dreg[it];
                const float4 f = freg[it];
                {   const int bk = d.x >> 7;
                    const int s  = base[bk] + atomicAdd(&hist[bk], 1);
                    if (s < bk * CAP + CAP)
                        pairs[s] = (__float_as_uint(f.x) & 0xFFFFFF00u) | (unsigned)(d.x & 127); }
                {   const int bk = d.y >> 7;
                    const int s  = base[bk] + atomicAdd(&hist[bk], 1);
                    if (s < bk * CAP + CAP)
                        pairs[s] = (__float_as_uint(f.y) & 0xFFFFFF00u) | (unsigned)(d.y & 127); }
                {   const int bk = d.z >> 7;
                    const int s  = base[bk] + atomicAdd(&hist[bk], 1);
                    if (s < bk * CAP + CAP)
                        pairs[s] = (__float_as_uint(f.z) & 0xFFFFFF00u) | (unsigned)(d.z & 127); }
                {   const int bk = d.w >> 7;
                    const int s  = base[bk] + atomicAdd(&hist[bk], 1);
                    if (s < bk * CAP + CAP)
                        pairs[s] = (__float_as_uint(f.w) & 0xFFFFFF00u) | (unsigned)(d.w & 127); }
            }
        }
    } else {
        const float* srcs[7] = {W1, Wm1, Wm2, Wm3, Wm4, Wr1, Wr2};
        const float* bias[7] = {b1, bm1, bm2, bm3, bm4, br1, br2};
        const int pb  = do_bin ? ((int)blockIdx.x - NBIN) : (int)blockIdx.x;
        const int gid = pb * 1024 + threadIdx.x;
        const int gsz = NPK * 1024;
        for (int i = gid; i < 425984; i += gsz) {
            int job, row, k, stride;
            if (i < 32768) { job = 0; row = i >> 7; k = i & 127; stride = 129; }
            else {
                int t = i - 32768; job = 1 + (t >> 16); int w = t & 65535;
                row = w >> 8; k = w & 255; stride = (job == 6) ? 256 : 257;
            }
            Wp[i] = (_Float16)srcs[job][row * stride + k];
        }
        for (int i = gid; i < 1536; i += gsz) {
            const int job = i >> 8, row = i & 255;
            const int stride = (job == 0) ? 129 : 257;
            const int kin    = (job == 0) ? 128 : 256;
            park[job * 512 + row] = srcs[job][row * stride + kin];
        }
        for (int i = gid; i < 256; i += gsz) park[6 * 512 + i] = 0.f;
        for (int i = gid; i < 1792; i += gsz)
            park[(i >> 8) * 512 + 256 + (i & 255)] = bias[i >> 8][i & 255];
        for (int i = gid; i < 256; i += gsz) park[3584 + i] = wr3[i];
        if (gid == 0) park[3840] = br3[0];
    }
}

// fallback: device-scope split-4 scatter (known-good)
__global__ void scatter4(const float4* __restrict__ ef4,
                         const int4* __restrict__ dst4,
                         float* __restrict__ e) {
    const int n4 = N_EDGES / 4;
    for (int i = blockIdx.x * blockDim.x + threadIdx.x; i < n4;
         i += gridDim.x * blockDim.x) {
        const float4 f = ef4[i];
        const int4   d = dst4[i];
        atomicAdd(&e[d.x], f.x);
        atomicAdd(&e[SH_STRIDE + d.y], f.y);
        atomicAdd(&e[2 * SH_STRIDE + d.z], f.z);
        atomicAdd(&e[3 * SH_STRIDE + d.w], f.w);
    }
}

// ---------------------------------------------------------------------------
// One layer over a 128-node tile (R5-proven shape). Wave owns 64 output cols
// x 128 nodes: jt4 x mt8. a-frag = W rows from global/L2, prefetched one
// k-step ahead; b-frag = H rows via ds_read_b128. Epilogue constants (we,
// bias) preloaded to REGISTERS from park (no LDS staging). Two barriers:
// post-K (Hs reads done) and post-epilogue (Hs writes visible).
// D: col=lane&15 -> node, row=quad*4+r -> 4 consecutive output features ->
// packed 8B LDS stores.
// ---------------------------------------------------------------------------
template<int K>
__device__ __forceinline__ void layer_mm(const _Float16* __restrict__ Wl,
                                         _Float16 (* __restrict__ Hs)[264],
                                         const float* __restrict__ es,
                                         const float* __restrict__ parkl,
                                         int wave, int m_, int quad) {
    f32x4 acc[4][8];
    #pragma unroll
    for (int jt = 0; jt < 4; ++jt)
        #pragma unroll
        for (int mt = 0; mt < 8; ++mt)
            acc[jt][mt] = (f32x4){0.f, 0.f, 0.f, 0.f};

    const int jb0 = wave * 64 + quad * 4;
    float4 w4[4], bb[4];
    #pragma unroll
    for (int jt = 0; jt < 4; ++jt) {
        w4[jt] = *(const float4*)&parkl[jt * 16 + jb0];
        bb[jt] = *(const float4*)&parkl[256 + jt * 16 + jb0];
    }

    const _Float16* __restrict__ wp = Wl + (size_t)(wave * 64 + m_) * K + quad * 8;

    half8 a[4];
    #pragma unroll
    for (int jt = 0; jt < 4; ++jt)
        a[jt] = *(const half8*)(wp + jt * 16 * K);

    #pragma unroll
    for (int kk = 0; kk < K; kk += 32) {
        half8 a2[4];
        if (kk + 32 < K) {
            #pragma unroll
            for (int jt = 0; jt < 4; ++jt)
                a2[jt] = *(const half8*)(wp + jt * 16 * K + kk + 32);
        }
        half8 b[8];
        #pragma unroll
        for (int mt = 0; mt < 8; ++mt)
            b[mt] = *(const half8*)&Hs[mt * 16 + m_][kk + quad * 8];
        #pragma unroll
        for (int jt = 0; jt < 4; ++jt)
            #pragma unroll
            for (int mt = 0; mt < 8; ++mt)
                acc[jt][mt] = __builtin_amdgcn_mfma_f32_16x16x32_f16(
                    a[jt], b[mt], acc[jt][mt], 0, 0, 0);
        if (kk + 32 < K) {
            #pragma unroll
            for (int jt = 0; jt < 4; ++jt) a[jt] = a2[jt];
        }
    }
    __syncthreads();   // all waves done reading Hs

    #pragma unroll
    for (int jt = 0; jt < 4; ++jt) {
        const int jbase = jb0 + jt * 16;
        #pragma unroll
        for (int mt = 0; mt < 8; ++mt) {
            const int node = mt * 16 + m_;
            const float ev = es[node];
            half4v h;
            h[0] = (_Float16)fmaxf(acc[jt][mt][0] + ev * w4[jt].x + bb[jt].x, 0.f);
            h[1] = (_Float16)fmaxf(acc[jt][mt][1] + ev * w4[jt].y + bb[jt].y, 0.f);
            h[2] = (_Float16)fmaxf(acc[jt][mt][2] + ev * w4[jt].z + bb[jt].z, 0.f);
            h[3] = (_Float16)fmaxf(acc[jt][mt][3] + ev * w4[jt].w + bb[jt].w, 0.f);
            *(half4v*)&Hs[node][jbase] = h;
        }
    }
    __syncthreads();   // Hs writes visible before next layer
}

// ---------------------------------------------------------------------------
__global__ __launch_bounds__(256, 2) void sage_fused(
    const float* __restrict__ node_feat,
    const int* __restrict__ cursor, const unsigned* __restrict__ pairs,
    const float* __restrict__ esh, int nsh,
    const _Float16* __restrict__ Wpack, const float* __restrict__ park,
    float* __restrict__ out) {

    __shared__ _Float16 Hs[128][264];   // +8-half pad
    __shared__ float es[128];
    __shared__ float wf[256];
    __shared__ float red[2][128];

    const int tid  = threadIdx.x;
    const int wave = tid >> 6;
    const int lane = tid & 63;
    const int m_   = lane & 15;
    const int quad = lane >> 4;
    const int node0 = blockIdx.x * 128;

    if (tid < 128) es[tid] = 0.f;
    __syncthreads();

    // ---- stage node_feat tile (fp32 -> fp16) ----
    for (int idx = tid; idx < 128 * 16; idx += 256) {
        const int row = idx >> 4, g = idx & 15;
        int node = node0 + row; if (node >= N_NODES) node = N_NODES - 1;
        const float4* src = (const float4*)(node_feat + (size_t)node * 128 + g * 8);
        const float4 v0 = src[0], v1 = src[1];
        half8 h;
        h[0] = (_Float16)v0.x; h[1] = (_Float16)v0.y;
        h[2] = (_Float16)v0.z; h[3] = (_Float16)v0.w;
        h[4] = (_Float16)v1.x; h[5] = (_Float16)v1.y;
        h[6] = (_Float16)v1.z; h[7] = (_Float16)v1.w;
        *(half8*)&Hs[row][g * 8] = h;
    }
    // ---- edge aggregate for this 128-node tile (1:1 bucket) ----
    if (nsh == 0) {
        const int cnt = min(cursor[blockIdx.x], CAP);
        const unsigned* __restrict__ pp = pairs + (size_t)blockIdx.x * CAP;
        for (int i = tid; i < cnt; i += 256) {
            const unsigned p = pp[i];
            atomicAdd(&es[p & 127u], __uint_as_float(p & 0xFFFFFF00u));
        }
    } else if (tid < 128) {
        int node = node0 + tid; if (node >= N_NODES) node = N_NODES - 1;
        float s = 0.f;
        for (int sh = 0; sh < nsh; ++sh) s += esh[(size_t)sh * SH_STRIDE + node];
        es[tid] = s;
    }
    __syncthreads();

    // layer 0: K=128; layers 1..6: K=256 (in-place Hs, 2 barriers each)
    layer_mm<128>(Wpack, Hs, es, park, wave, m_, quad);
    for (int l = 1; l < 7; ++l)
        layer_mm<256>(Wpack + 32768 + (l - 1) * 65536, Hs, es, park + l * 512,
                      wave, m_, quad);

    // ---- final 256 -> 1 dot (fp32) ----
    wf[tid] = park[3584 + tid];
    __syncthreads();
    {
        const int row = tid & 127, seg = tid >> 7;
        const _Float16* hp = &Hs[row][seg * 128];
        const float* wpt = &wf[seg * 128];
        float s = 0.f;
        #pragma unroll 8
        for (int k = 0; k < 128; ++k) s += (float)hp[k] * wpt[k];
        red[seg][row] = s;
    }
    __syncthreads();
    if (tid < 128) {
        const int node = node0 + tid;
        if (node < N_NODES)
            out[node] = red[0][tid] + red[1][tid] + park[3840];
    }
}

// ---------------------------------------------------------------------------
extern "C" void kernel_launch(void* const* d_in, const int* in_sizes, int n_in,
                              void* d_out, int out_size, void* d_ws,
                              size_t ws_size, hipStream_t stream) {
    const float* node_feat = (const float*)d_in[0];
    const float* edge_feat = (const float*)d_in[1];
    const int*   edge_dst  = (const int*)d_in[2];
    const float* W1  = (const float*)d_in[3];  const float* b1  = (const float*)d_in[4];
    const float* Wm1 = (const float*)d_in[5];  const float* bm1 = (const float*)d_in[6];
    const float* Wm2 = (const float*)d_in[7];  const float* bm2 = (const float*)d_in[8];
    const float* Wm3 = (const float*)d_in[9];  const float* bm3 = (const float*)d_in[10];
    const float* Wm4 = (const float*)d_in[11]; const float* bm4 = (const float*)d_in[12];
    const float* Wr1 = (const float*)d_in[13]; const float* br1 = (const float*)d_in[14];
    const float* Wr2 = (const float*)d_in[15]; const float* br2 = (const float*)d_in[16];
    const float* Wr3 = (const float*)d_in[17]; const float* br3 = (const float*)d_in[18];
    float* out = (float*)d_out;

    // ws layout: cursor | Wp | park | pairs (or fallback shadows)
    char* ws = (char*)d_ws;
    int*      cursor = (int*)ws;                           // 4096 B reserved
    _Float16* Wp     = (_Float16*)(ws + 4096);             // 851968 B
    float*    park   = (float*)(ws + 856064);              // 16384 B
    unsigned* pairs  = (unsigned*)(ws + 872448);           // NBUCK*CAP*4 B
    float*    esh    = (float*)(ws + 872448);              // fallback shadows

    const size_t need_bins = 872448 + (size_t)NBUCK * CAP * 4;   // ~16.9 MB
    const bool use_bins = (ws_size >= need_bins);

    const int nblk = (N_NODES + 127) / 128;   // 782

    if (use_bins) {
        hipMemsetAsync(cursor, 0, NBUCK * sizeof(int), stream);
        binpack<<<NBIN + NPK, 1024, 0, stream>>>(
            edge_feat, edge_dst, W1, Wm1, Wm2, Wm3, Wm4, Wr1, Wr2,
            b1, bm1, bm2, bm3, bm4, br1, br2, Wr3, br3,
            cursor, pairs, Wp, park, 1);
        sage_fused<<<nblk, 256, 0, stream>>>(node_feat, cursor, pairs,
                                             nullptr, 0, Wp, park, out);
    } else {
        binpack<<<NPK, 1024, 0, stream>>>(
            edge_feat, edge_dst, W1, Wm1, Wm2, Wm3, Wm4, Wr1, Wr2,
            b1, bm1, bm2, bm3, bm4, br1, br2, Wr3, br3,
            cursor, pairs, Wp, park, 0);
        hipMemsetAsync(esh, 0, (size_t)4 * SH_STRIDE * 4, stream);
        scatter4<<<3125, 256, 0, stream>>>((const float4*)edge_feat,
                                           (const int4*)edge_dst, esh);
        sage_fused<<<nblk, 256, 0, stream>>>(node_feat, nullptr, nullptr,
                                             esh, 4, Wp, park, out);
    }
}